// Round 17
// baseline (127.026 us; speedup 1.0000x reference)
//
#include <hip/hip_runtime.h>
#include <stdint.h>

#define BB 4
#define SS 4096
#define DD 1024
#define FF 4096
#define CAP 512
#define MTOT (BB*CAP)          // 2048
#define NOUT (BB*SS*DD)        // 16777216

typedef unsigned short ushort_t;
typedef float  float4v  __attribute__((ext_vector_type(4)));
typedef short  short8v  __attribute__((ext_vector_type(8)));
typedef unsigned short ushort4v __attribute__((ext_vector_type(4)));

// ws layout (bytes)
#define OFF_RW   0u             // B*S f32 = 64KB
#define OFF_IDX  (64u*1024u)    // 2048 int = 8KB
#define OFF_WTOP (72u*1024u)    // 2048 f32 = 8KB
#define OFF_LOSS (80u*1024u)    // 4 f32 per-batch loss
#define OFF_POS  (128u*1024u)   // B*S int = 64KB
#define OFF_RANK (256u*1024u)   // B*S int = 64KB
#define OFF_A    (1u<<20)       // MTOT*D bf16 = 4MB
#define OFF_W1T  (5u<<20)       // F*D bf16 = 8MB
#define OFF_W2T  (13u<<20)      // D*F bf16 = 8MB
#define OFF_H    (21u<<20)      // MTOT*F bf16 = 16MB (ends 37MB)
#define OFF_O    (37u<<20)      // 4 x MTOT*D bf16 = 16MB split-K partials (ends 53MB)

#define GLD16(gsrc, ldst) __builtin_amdgcn_global_load_lds( \
    (const __attribute__((address_space(1))) void*)(gsrc),  \
    (__attribute__((address_space(3))) void*)(ldst), 16, 0, 0)

__device__ inline ushort_t f2bf(float f) {
  uint32_t u = __builtin_bit_cast(uint32_t, f);
  u = u + 0x7fffu + ((u >> 16) & 1u);
  return (ushort_t)(u >> 16);
}
__device__ inline float bf2f(ushort_t h) {
  uint32_t u = (uint32_t)h << 16;
  return __builtin_bit_cast(float, u);
}

// ---------------- router: rw = sigmoid(x . w) ----------------
__global__ void router_kernel(const float* __restrict__ x, const float* __restrict__ w,
                              float* __restrict__ rw) {
  int wave = threadIdx.x >> 6;
  int lane = threadIdx.x & 63;
  int row  = blockIdx.x * 4 + wave;            // [0, B*S)
  const float4* xr = (const float4*)(x + (size_t)row * DD);
  const float4* wr = (const float4*)w;
  float s = 0.f;
#pragma unroll
  for (int i = 0; i < 4; i++) {
    float4 a = xr[lane + i * 64];
    float4 b = wr[lane + i * 64];
    s += a.x * b.x + a.y * b.y + a.z * b.z + a.w * b.w;
  }
#pragma unroll
  for (int off = 32; off > 0; off >>= 1) s += __shfl_xor(s, off, 64);
  if (lane == 0) rw[row] = 1.f / (1.f + expf(-s));
}

// ---------------- rank: rank[i] = |{j: v_j>v_i or (v_j==v_i && j<i)}| ----------------
__global__ __launch_bounds__(256) void rank_kernel(const float* __restrict__ rw,
                                                   int* __restrict__ rank) {
  __shared__ float v[SS];
  const int b = blockIdx.y;
  const float* rwg = rw + (size_t)b * SS;
  for (int m = threadIdx.x; m < SS / 4; m += 256)
    ((float4*)v)[m] = ((const float4*)rwg)[m];
  __syncthreads();
  const int e = blockIdx.x * 64 + (threadIdx.x >> 2);
  const int part = threadIdx.x & 3;
  const float vi = v[e];
  const int j0 = part * (SS / 4);
  int cnt = 0;
#pragma unroll 4
  for (int j4 = 0; j4 < SS / 16; ++j4) {
    float4 w = ((const float4*)(v + j0))[j4];
    int j = j0 + j4 * 4;
    cnt += (w.x > vi || (w.x == vi && (j + 0) < e));
    cnt += (w.y > vi || (w.y == vi && (j + 1) < e));
    cnt += (w.z > vi || (w.z == vi && (j + 2) < e));
    cnt += (w.w > vi || (w.w == vi && (j + 3) < e));
  }
  cnt += __shfl_xor(cnt, 1, 64);
  cnt += __shfl_xor(cnt, 2, 64);
  if (part == 0) rank[(size_t)b * SS + e] = cnt;
}

// ---------------- finalize: compact selected (rank<CAP) in index order ----------------
__global__ __launch_bounds__(1024) void finalize_kernel(const float* __restrict__ rw,
                                                        const int* __restrict__ rank,
                                                        int* __restrict__ idxs,
                                                        float* __restrict__ wtop,
                                                        int* __restrict__ posmap,
                                                        float* __restrict__ lossP) {
  __shared__ int   wsumI[16];
  __shared__ float wsumF[16];
  const int b = blockIdx.x, tid = threadIdx.x;
  const int lane = tid & 63, wv = tid >> 6;
  const float* rwg = rw + (size_t)b * SS;
  const int*   rkg = rank + (size_t)b * SS;
  const int m0 = tid * 4;
  int rk[4]; float rv[4];
  int cnt = 0;
#pragma unroll
  for (int u = 0; u < 4; u++) {
    rk[u] = rkg[m0 + u]; rv[u] = rwg[m0 + u];
    cnt += (rk[u] < CAP);
  }
  int val = cnt;
#pragma unroll
  for (int off = 1; off < 64; off <<= 1) {
    int n = __shfl_up(val, off, 64);
    if (lane >= off) val += n;
  }
  if (lane == 63) wsumI[wv] = val;
  __syncthreads();
  int wbase = 0;
  for (int w = 0; w < wv; ++w) wbase += wsumI[w];
  int excl = wbase + val - cnt;   // exclusive prefix for this thread
#pragma unroll
  for (int u = 0; u < 4; u++) {
    int m = m0 + u;
    if (rk[u] < CAP) {
      int pos = excl++;
      idxs[b * CAP + pos] = m;
      wtop[b * CAP + pos] = rwg[rk[u]];     // faithful quirk: rw at position rank (<CAP)
      posmap[(size_t)b * SS + m] = b * CAP + pos;
    } else {
      posmap[(size_t)b * SS + m] = -1;
    }
  }
  float ls = 0.f;
#pragma unroll
  for (int u = 0; u < 4; u++) {
    float term = (rk[u] < CAP) ? logf(rv[u]) : log1pf(-rv[u]);
    ls += fmaxf(term, -100.f);
  }
#pragma unroll
  for (int off = 32; off > 0; off >>= 1) ls += __shfl_xor(ls, off, 64);
  if (lane == 0) wsumF[wv] = ls;
  __syncthreads();
  if (tid == 0) {
    float t = 0.f;
    for (int i = 0; i < 16; i++) t += wsumF[i];
    lossP[b] = t;
  }
}

// ------- prep: both weight transposes + A gather, one launch ------------------------
__global__ __launch_bounds__(256) void prep_kernel(const float* __restrict__ W1,
                                                   ushort_t* __restrict__ W1T,
                                                   const float* __restrict__ W2,
                                                   ushort_t* __restrict__ W2T,
                                                   const float* __restrict__ x,
                                                   const int* __restrict__ idxs,
                                                   ushort_t* __restrict__ A) {
  int id = blockIdx.x;
  const int tid = threadIdx.x;
  if (id < 8192) {
    __shared__ float t[32][33];
    const float* in; ushort_t* out; int R, C, bx, by;
    if (id < (FF / 32) * (DD / 32)) {           // W1: R=DD rows, C=FF cols
      in = W1; out = W1T; R = DD; C = FF;
      bx = id % (FF / 32); by = id / (FF / 32);
    } else {                                    // W2: R=FF rows, C=DD cols
      id -= (FF / 32) * (DD / 32);
      in = W2; out = W2T; R = FF; C = DD;
      bx = id % (DD / 32); by = id / (DD / 32);
    }
    const int c0 = bx * 32, r0 = by * 32;
    const int tx = tid & 7;    // 0..7
    const int ty = tid >> 3;   // 0..31
    const float4 vv = *(const float4*)&in[(size_t)(r0 + ty) * C + c0 + tx * 4];
    t[ty][tx * 4 + 0] = vv.x; t[ty][tx * 4 + 1] = vv.y;
    t[ty][tx * 4 + 2] = vv.z; t[ty][tx * 4 + 3] = vv.w;
    __syncthreads();
    ushort4v o;
    o[0] = f2bf(t[tx * 4 + 0][ty]); o[1] = f2bf(t[tx * 4 + 1][ty]);
    o[2] = f2bf(t[tx * 4 + 2][ty]); o[3] = f2bf(t[tx * 4 + 3][ty]);
    *(ushort4v*)&out[(size_t)(c0 + ty) * R + r0 + tx * 4] = o;
  } else {
    int row = id - 8192;                  // [0, MTOT)
    int b = row >> 9;
    int seq = idxs[row];
    const float4* src = (const float4*)(x + ((size_t)(b * SS + seq)) * DD);
    float4 a = src[tid];
    ushort4v o;
    o[0] = f2bf(a.x); o[1] = f2bf(a.y); o[2] = f2bf(a.z); o[3] = f2bf(a.w);
    *(ushort4v*)(A + (size_t)row * DD + tid * 4) = o;
  }
}

// ------- final: out[row] = p>=0 ? (sum of 4 bf16 partials)[p]*wtop[p] : 0 ; + loss --
__global__ void scatter_kernel(const ushort_t* __restrict__ O, const int* __restrict__ posmap,
                               const float* __restrict__ wtop, const float* __restrict__ lossP,
                               float* __restrict__ out) {
  int r = blockIdx.x;                   // [0, B*S)
  int p = posmap[r];
  float4 v = {0.f, 0.f, 0.f, 0.f};
  if (p >= 0) {
    float wt = wtop[p];
    const size_t stride = (size_t)MTOT * DD;
    const size_t off = (size_t)p * DD + threadIdx.x * 4;
    ushort4v h0 = *(const ushort4v*)(O + off);
    ushort4v h1 = *(const ushort4v*)(O + stride + off);
    ushort4v h2 = *(const ushort4v*)(O + 2 * stride + off);
    ushort4v h3 = *(const ushort4v*)(O + 3 * stride + off);
    v.x = ((bf2f(h0[0]) + bf2f(h1[0])) + (bf2f(h2[0]) + bf2f(h3[0]))) * wt;
    v.y = ((bf2f(h0[1]) + bf2f(h1[1])) + (bf2f(h2[1]) + bf2f(h3[1]))) * wt;
    v.z = ((bf2f(h0[2]) + bf2f(h1[2])) + (bf2f(h2[2]) + bf2f(h3[2]))) * wt;
    v.w = ((bf2f(h0[3]) + bf2f(h1[3])) + (bf2f(h2[3]) + bf2f(h3[3]))) * wt;
  }
  ((float4*)(out + (size_t)r * DD))[threadIdx.x] = v;
  if (r == 0 && threadIdx.x == 0)
    out[NOUT] = -(lossP[0] + lossP[1] + lossP[2] + lossP[3]) / (float)(BB * SS);
}

// ---------------- GEMM: 64x64 tile, BK=64, DOUBLE-BUFFERED bottom-drain -------------
// 4 waves, wave tile 32x32. 2x16KB LDS = 32KB -> 5 blocks/CU. Loop: STAGE(next) ->
// compute(cur) -> vmcnt(0)+s_barrier -> swap. Within-block latency hiding composes
// with sibling-block cover. 2D XCD-tiled decode keeps each XCD's operands <=4MB (L2).
// LDS swizzle: phys slot p of row r holds global k-slot p^(r&7) (inverse-swizzled
// SOURCE, linear gld_lds DEST; ds_read applies same XOR).
// MODE 0: gelu epilogue (x*sigmoid(2u) identity) -> Hout bf16 [M][FF]
// MODE 1: direct store of bf16 partial to Oacc + bz*MTOT*DD (no atomics)
template <int MODE>
__global__ __launch_bounds__(256) void gemm_oc(const ushort_t* __restrict__ Ag,
                                               const ushort_t* __restrict__ Bg, int Kstride,
                                               ushort_t* __restrict__ Hout,
                                               ushort_t* __restrict__ Oacc) {
  __shared__ ushort_t lA[2][64 * 64];   // 8KB per buffer
  __shared__ ushort_t lB[2][64 * 64];
  const int tid = threadIdx.x;
  const int lane = tid & 63, wv = tid >> 6;
  const int wr = wv >> 1, wc = wv & 1;     // 2M x 2N wave grid, wave tile 32x32

  const int gx = gridDim.x, gy = gridDim.y;
  const int id = blockIdx.x + gx * (blockIdx.y + gy * blockIdx.z);
  const int xcd = id & 7, q = id >> 3;     // q in [0,256)

  int bm0, bn0, bz, kbeg;
  if (MODE == 0) {
    const int mx = (xcd & 1) * 16 + (q & 15);        // 0..31
    const int nx = (xcd >> 1) * 16 + (q >> 4);       // 0..63
    bm0 = mx * 64; bn0 = nx * 64; bz = 0; kbeg = 0;
  } else {
    bz = xcd >> 1;                                   // 0..3
    const int by = (xcd & 1) * 16 + (q & 15);        // 0..31
    const int bx = q >> 4;                           // 0..15
    bm0 = by * 64; bn0 = bx * 64; kbeg = bz * (Kstride >> 2);
  }
  const int kchunk = (MODE == 0) ? Kstride : (Kstride >> 2);
  const int nkt = kchunk / 64;             // 16 K-steps for both GEMMs

  const int srow = lane >> 3;              // 0..7
  const int gslot = (lane & 7) ^ srow;     // inverse-swizzled global 16B slot

  float4v acc[2][2];
#pragma unroll
  for (int i = 0; i < 2; i++)
#pragma unroll
    for (int j = 0; j < 2; j++) acc[i][j] = (float4v){0.f, 0.f, 0.f, 0.f};

#define STAGE(buf, k0)                                                              \
  {                                                                                 \
    _Pragma("unroll")                                                               \
    for (int i = 0; i < 2; i++) {                                                   \
      const int row = i * 32 + wv * 8 + srow;                                       \
      const int chunkbase = i * 256 + wv * 64;                                      \
      GLD16(Ag + (size_t)(bm0 + row) * Kstride + (k0) + gslot * 8, &lA[buf][chunkbase * 8]); \
      GLD16(Bg + (size_t)(bn0 + row) * Kstride + (k0) + gslot * 8, &lB[buf][chunkbase * 8]); \
    }                                                                               \
  }

  // prologue: buffer 0 resident
  STAGE(0, kbeg);
  asm volatile("s_waitcnt vmcnt(0)" ::: "memory");
  asm volatile("s_barrier" ::: "memory");

  int cur = 0;
  for (int t = 0; t < nkt; ++t) {
    if (t + 1 < nkt) STAGE(cur ^ 1, kbeg + (t + 1) * 64);   // issue next under compute
#pragma unroll
    for (int kk = 0; kk < 2; kk++) {
      const int s = (lane >> 4) + kk * 4;   // logical 16B k-slot 0..7
      short8v af[2], bfr[2];
#pragma unroll
      for (int mi = 0; mi < 2; mi++) {
        const int rr = wr * 32 + mi * 16 + (lane & 15);
        af[mi] = *(const short8v*)&lA[cur][rr * 64 + (s ^ (rr & 7)) * 8];
      }
#pragma unroll
      for (int nj = 0; nj < 2; nj++) {
        const int rr = wc * 32 + nj * 16 + (lane & 15);
        bfr[nj] = *(const short8v*)&lB[cur][rr * 64 + (s ^ (rr & 7)) * 8];
      }
#pragma unroll
      for (int mi = 0; mi < 2; mi++)
#pragma unroll
        for (int nj = 0; nj < 2; nj++)
          acc[mi][nj] = __builtin_amdgcn_mfma_f32_16x16x32_bf16(af[mi], bfr[nj], acc[mi][nj], 0, 0, 0);
    }
    if (t + 1 < nkt) {
      asm volatile("s_waitcnt vmcnt(0)" ::: "memory");   // next buffer landed
      asm volatile("s_barrier" ::: "memory");            // all waves done reading cur
    }
    cur ^= 1;
  }
#undef STAGE

  if (MODE == 0) {
#pragma unroll
    for (int mi = 0; mi < 2; mi++) {
      int r0 = bm0 + wr * 32 + mi * 16 + ((lane >> 4) << 2);
#pragma unroll
      for (int nj = 0; nj < 2; nj++) {
        int cc = bn0 + wc * 32 + nj * 16 + (lane & 15);
#pragma unroll
        for (int r = 0; r < 4; r++) {
          float xv = acc[mi][nj][r];
          // gelu(x) = 0.5x(1+tanh(u)) == x * sigmoid(2u); u = 0.79788456(x+0.044715x^3)
          float u = 0.7978845608028654f * (xv + 0.044715f * xv * xv * xv);
          float g = xv / (1.f + __expf(-2.f * u));
          Hout[(size_t)(r0 + r) * FF + cc] = f2bf(g);
        }
      }
    }
  } else {
    ushort_t* Op = Oacc + (size_t)bz * MTOT * DD;   // disjoint bf16 partial per K-split
#pragma unroll
    for (int mi = 0; mi < 2; mi++) {
      int tr0 = bm0 + wr * 32 + mi * 16 + ((lane >> 4) << 2);
#pragma unroll
      for (int r = 0; r < 4; r++) {
        ushort_t* orow = Op + (size_t)(tr0 + r) * DD + bn0 + wc * 32 + (lane & 15);
#pragma unroll
        for (int nj = 0; nj < 2; nj++) orow[nj * 16] = f2bf(acc[mi][nj][r]);
      }
    }
  }
}

extern "C" void kernel_launch(void* const* d_in, const int* in_sizes, int n_in,
                              void* d_out, int out_size, void* d_ws, size_t ws_size,
                              hipStream_t stream) {
  (void)in_sizes; (void)n_in; (void)out_size; (void)ws_size;
  const float* x  = (const float*)d_in[0];
  const float* wrt = (const float*)d_in[1];
  const float* W1 = (const float*)d_in[2];
  const float* W2 = (const float*)d_in[3];
  float* out = (float*)d_out;
  char* ws = (char*)d_ws;
  float*    rw   = (float*)(ws + OFF_RW);
  int*      idxs = (int*)(ws + OFF_IDX);
  float*    wtop = (float*)(ws + OFF_WTOP);
  float*    lossP= (float*)(ws + OFF_LOSS);
  int*      posm = (int*)(ws + OFF_POS);
  int*      rnk  = (int*)(ws + OFF_RANK);
  ushort_t* A    = (ushort_t*)(ws + OFF_A);
  ushort_t* W1T  = (ushort_t*)(ws + OFF_W1T);
  ushort_t* W2T  = (ushort_t*)(ws + OFF_W2T);
  ushort_t* H    = (ushort_t*)(ws + OFF_H);
  ushort_t* O    = (ushort_t*)(ws + OFF_O);

  // no memsets: every scratch value consumed is written each call
  router_kernel<<<dim3(BB * SS / 4), dim3(256), 0, stream>>>(x, wrt, rw);
  rank_kernel<<<dim3(SS / 64, BB), dim3(256), 0, stream>>>(rw, rnk);
  finalize_kernel<<<dim3(BB), dim3(1024), 0, stream>>>(rw, rnk, idxs, wtop, posm, lossP);
  prep_kernel<<<dim3(8192 + MTOT), dim3(256), 0, stream>>>(W1, W1T, W2, W2T, x, idxs, A);
  // GEMM1: [2048x1024]*[4096x1024]^T -> gelu -> H    grid (64,32)=2048 blocks
  gemm_oc<0><<<dim3(FF / 64, MTOT / 64, 1), dim3(256), 0, stream>>>(A, W1T, DD, H, nullptr);
  // GEMM2: [2048x4096]*[1024x4096]^T -> 4 bf16 direct-store partials, grid (16,32,4)
  gemm_oc<1><<<dim3(DD / 64, MTOT / 64, 4), dim3(256), 0, stream>>>(H, W2T, FF, nullptr, O);
  // final: every d_out row written exactly once; loss element in block 0
  scatter_kernel<<<dim3(BB * SS), dim3(256), 0, stream>>>(O, posm, wtop, lossP, out);
}

// Round 18
// 125.912 us; speedup vs baseline: 1.0088x; 1.0088x over previous
//
#include <hip/hip_runtime.h>
#include <stdint.h>

#define BB 4
#define SS 4096
#define DD 1024
#define FF 4096
#define CAP 512
#define MTOT (BB*CAP)          // 2048
#define NOUT (BB*SS*DD)        // 16777216

typedef unsigned short ushort_t;
typedef float  float4v  __attribute__((ext_vector_type(4)));
typedef short  short8v  __attribute__((ext_vector_type(8)));
typedef unsigned short ushort4v __attribute__((ext_vector_type(4)));

// ws layout (bytes)
#define OFF_RW   0u             // B*S f32 = 64KB
#define OFF_IDX  (64u*1024u)    // 2048 int = 8KB
#define OFF_WTOP (72u*1024u)    // 2048 f32 = 8KB
#define OFF_LOSS (80u*1024u)    // 4 f32 per-batch loss
#define OFF_POS  (128u*1024u)   // B*S int = 64KB
#define OFF_RANK (256u*1024u)   // B*S int = 64KB
#define OFF_A    (1u<<20)       // MTOT*D bf16 = 4MB
#define OFF_W1T  (5u<<20)       // F*D bf16 = 8MB
#define OFF_W2T  (13u<<20)      // D*F bf16 = 8MB
#define OFF_H    (21u<<20)      // MTOT*F bf16 = 16MB (ends 37MB)
#define OFF_O    (37u<<20)      // 4 x MTOT*D bf16 = 16MB split-K partials (ends 53MB)

#define GLD16(gsrc, ldst) __builtin_amdgcn_global_load_lds( \
    (const __attribute__((address_space(1))) void*)(gsrc),  \
    (__attribute__((address_space(3))) void*)(ldst), 16, 0, 0)

__device__ inline ushort_t f2bf(float f) {
  uint32_t u = __builtin_bit_cast(uint32_t, f);
  u = u + 0x7fffu + ((u >> 16) & 1u);
  return (ushort_t)(u >> 16);
}
__device__ inline float bf2f(ushort_t h) {
  uint32_t u = (uint32_t)h << 16;
  return __builtin_bit_cast(float, u);
}

// ---------------- router: rw = sigmoid(x . w) ----------------
__global__ void router_kernel(const float* __restrict__ x, const float* __restrict__ w,
                              float* __restrict__ rw) {
  int wave = threadIdx.x >> 6;
  int lane = threadIdx.x & 63;
  int row  = blockIdx.x * 4 + wave;            // [0, B*S)
  const float4* xr = (const float4*)(x + (size_t)row * DD);
  const float4* wr = (const float4*)w;
  float s = 0.f;
#pragma unroll
  for (int i = 0; i < 4; i++) {
    float4 a = xr[lane + i * 64];
    float4 b = wr[lane + i * 64];
    s += a.x * b.x + a.y * b.y + a.z * b.z + a.w * b.w;
  }
#pragma unroll
  for (int off = 32; off > 0; off >>= 1) s += __shfl_xor(s, off, 64);
  if (lane == 0) rw[row] = 1.f / (1.f + expf(-s));
}

// ---------------- rank: rank[i] = |{j: v_j>v_i or (v_j==v_i && j<i)}| ----------------
__global__ __launch_bounds__(256) void rank_kernel(const float* __restrict__ rw,
                                                   int* __restrict__ rank) {
  __shared__ float v[SS];
  const int b = blockIdx.y;
  const float* rwg = rw + (size_t)b * SS;
  for (int m = threadIdx.x; m < SS / 4; m += 256)
    ((float4*)v)[m] = ((const float4*)rwg)[m];
  __syncthreads();
  const int e = blockIdx.x * 64 + (threadIdx.x >> 2);
  const int part = threadIdx.x & 3;
  const float vi = v[e];
  const int j0 = part * (SS / 4);
  int cnt = 0;
#pragma unroll 4
  for (int j4 = 0; j4 < SS / 16; ++j4) {
    float4 w = ((const float4*)(v + j0))[j4];
    int j = j0 + j4 * 4;
    cnt += (w.x > vi || (w.x == vi && (j + 0) < e));
    cnt += (w.y > vi || (w.y == vi && (j + 1) < e));
    cnt += (w.z > vi || (w.z == vi && (j + 2) < e));
    cnt += (w.w > vi || (w.w == vi && (j + 3) < e));
  }
  cnt += __shfl_xor(cnt, 1, 64);
  cnt += __shfl_xor(cnt, 2, 64);
  if (part == 0) rank[(size_t)b * SS + e] = cnt;
}

// ---------------- finalize: compact selected (rank<CAP) in index order ----------------
__global__ __launch_bounds__(1024) void finalize_kernel(const float* __restrict__ rw,
                                                        const int* __restrict__ rank,
                                                        int* __restrict__ idxs,
                                                        float* __restrict__ wtop,
                                                        int* __restrict__ posmap,
                                                        float* __restrict__ lossP) {
  __shared__ int   wsumI[16];
  __shared__ float wsumF[16];
  const int b = blockIdx.x, tid = threadIdx.x;
  const int lane = tid & 63, wv = tid >> 6;
  const float* rwg = rw + (size_t)b * SS;
  const int*   rkg = rank + (size_t)b * SS;
  const int m0 = tid * 4;
  int rk[4]; float rv[4];
  int cnt = 0;
#pragma unroll
  for (int u = 0; u < 4; u++) {
    rk[u] = rkg[m0 + u]; rv[u] = rwg[m0 + u];
    cnt += (rk[u] < CAP);
  }
  int val = cnt;
#pragma unroll
  for (int off = 1; off < 64; off <<= 1) {
    int n = __shfl_up(val, off, 64);
    if (lane >= off) val += n;
  }
  if (lane == 63) wsumI[wv] = val;
  __syncthreads();
  int wbase = 0;
  for (int w = 0; w < wv; ++w) wbase += wsumI[w];
  int excl = wbase + val - cnt;   // exclusive prefix for this thread
#pragma unroll
  for (int u = 0; u < 4; u++) {
    int m = m0 + u;
    if (rk[u] < CAP) {
      int pos = excl++;
      idxs[b * CAP + pos] = m;
      wtop[b * CAP + pos] = rwg[rk[u]];     // faithful quirk: rw at position rank (<CAP)
      posmap[(size_t)b * SS + m] = b * CAP + pos;
    } else {
      posmap[(size_t)b * SS + m] = -1;
    }
  }
  float ls = 0.f;
#pragma unroll
  for (int u = 0; u < 4; u++) {
    float term = (rk[u] < CAP) ? logf(rv[u]) : log1pf(-rv[u]);
    ls += fmaxf(term, -100.f);
  }
#pragma unroll
  for (int off = 32; off > 0; off >>= 1) ls += __shfl_xor(ls, off, 64);
  if (lane == 0) wsumF[wv] = ls;
  __syncthreads();
  if (tid == 0) {
    float t = 0.f;
    for (int i = 0; i < 16; i++) t += wsumF[i];
    lossP[b] = t;
  }
}

// ------- prep: both weight transposes + A gather, one launch ------------------------
// blocks [0, 8192): transpose W1/W2 (f32 [R][C] -> bf16 [C][R], 32x32 tiles)
// blocks [8192, 10240): gather selected x rows -> bf16 A
__global__ __launch_bounds__(256) void prep_kernel(const float* __restrict__ W1,
                                                   ushort_t* __restrict__ W1T,
                                                   const float* __restrict__ W2,
                                                   ushort_t* __restrict__ W2T,
                                                   const float* __restrict__ x,
                                                   const int* __restrict__ idxs,
                                                   ushort_t* __restrict__ A) {
  int id = blockIdx.x;
  const int tid = threadIdx.x;
  if (id < 8192) {
    __shared__ float t[32][33];
    const float* in; ushort_t* out; int R, C, bx, by;
    if (id < (FF / 32) * (DD / 32)) {           // W1: R=DD rows, C=FF cols
      in = W1; out = W1T; R = DD; C = FF;
      bx = id % (FF / 32); by = id / (FF / 32);
    } else {                                    // W2: R=FF rows, C=DD cols
      id -= (FF / 32) * (DD / 32);
      in = W2; out = W2T; R = FF; C = DD;
      bx = id % (DD / 32); by = id / (DD / 32);
    }
    const int c0 = bx * 32, r0 = by * 32;
    const int tx = tid & 7;    // 0..7
    const int ty = tid >> 3;   // 0..31
    const float4 vv = *(const float4*)&in[(size_t)(r0 + ty) * C + c0 + tx * 4];
    t[ty][tx * 4 + 0] = vv.x; t[ty][tx * 4 + 1] = vv.y;
    t[ty][tx * 4 + 2] = vv.z; t[ty][tx * 4 + 3] = vv.w;
    __syncthreads();
    ushort4v o;
    o[0] = f2bf(t[tx * 4 + 0][ty]); o[1] = f2bf(t[tx * 4 + 1][ty]);
    o[2] = f2bf(t[tx * 4 + 2][ty]); o[3] = f2bf(t[tx * 4 + 3][ty]);
    *(ushort4v*)&out[(size_t)(c0 + ty) * R + r0 + tx * 4] = o;
  } else {
    int row = id - 8192;                  // [0, MTOT)
    int b = row >> 9;
    int seq = idxs[row];
    const float4* src = (const float4*)(x + ((size_t)(b * SS + seq)) * DD);
    float4 a = src[tid];
    ushort4v o;
    o[0] = f2bf(a.x); o[1] = f2bf(a.y); o[2] = f2bf(a.z); o[3] = f2bf(a.w);
    *(ushort4v*)(A + (size_t)row * DD + tid * 4) = o;
  }
}

// ------- final: out[row] = p>=0 ? (sum of 4 bf16 partials)[p]*wtop[p] : 0 ; + loss --
__global__ void scatter_kernel(const ushort_t* __restrict__ O, const int* __restrict__ posmap,
                               const float* __restrict__ wtop, const float* __restrict__ lossP,
                               float* __restrict__ out) {
  int r = blockIdx.x;                   // [0, B*S)
  int p = posmap[r];
  float4 v = {0.f, 0.f, 0.f, 0.f};
  if (p >= 0) {
    float wt = wtop[p];
    const size_t stride = (size_t)MTOT * DD;
    const size_t off = (size_t)p * DD + threadIdx.x * 4;
    ushort4v h0 = *(const ushort4v*)(O + off);
    ushort4v h1 = *(const ushort4v*)(O + stride + off);
    ushort4v h2 = *(const ushort4v*)(O + 2 * stride + off);
    ushort4v h3 = *(const ushort4v*)(O + 3 * stride + off);
    v.x = ((bf2f(h0[0]) + bf2f(h1[0])) + (bf2f(h2[0]) + bf2f(h3[0]))) * wt;
    v.y = ((bf2f(h0[1]) + bf2f(h1[1])) + (bf2f(h2[1]) + bf2f(h3[1]))) * wt;
    v.z = ((bf2f(h0[2]) + bf2f(h1[2])) + (bf2f(h2[2]) + bf2f(h3[2]))) * wt;
    v.w = ((bf2f(h0[3]) + bf2f(h1[3])) + (bf2f(h2[3]) + bf2f(h3[3]))) * wt;
  }
  ((float4*)(out + (size_t)r * DD))[threadIdx.x] = v;
  if (r == 0 && threadIdx.x == 0)
    out[NOUT] = -(lossP[0] + lossP[1] + lossP[2] + lossP[3]) / (float)(BB * SS);
}

// ---------------- GEMM: 64x64 tile, BK=128 (two 64-planes, ONE barrier pair) --------
// 4 waves, wave tile 32x32. LDS 32KB -> 5 blocks/CU. 2D XCD-tiled decode: each XCD's
// 256 blocks share a <=4MB operand working set (L2-fit).
// MODE 0: M-tiles 32 x N-tiles 64; XCD covers 16Mx16N square (A 2MB + B 2MB).
// MODE 1: M 32 x N 16 x Z 4; XCD = fixed bz + 16by x 16bx (H 2MB + W2T 2MB).
// LDS swizzle per plane: phys slot p of row r holds global k-slot p^(r&7)
// (inverse-swizzled SOURCE, linear gld_lds DEST; ds_read applies same XOR).
// MODE 0 epilogue: gelu via x*sigmoid(2u) identity -> Hout bf16 [M][FF]
// MODE 1 epilogue: direct store of bf16 partial to Oacc + bz*MTOT*DD (no atomics)
template <int MODE>
__global__ __launch_bounds__(256) void gemm_oc(const ushort_t* __restrict__ Ag,
                                               const ushort_t* __restrict__ Bg, int Kstride,
                                               ushort_t* __restrict__ Hout,
                                               ushort_t* __restrict__ Oacc) {
  __shared__ ushort_t lA[2][64 * 64];   // two K-planes, 16KB
  __shared__ ushort_t lB[2][64 * 64];   // 16KB
  const int tid = threadIdx.x;
  const int lane = tid & 63, wv = tid >> 6;
  const int wr = wv >> 1, wc = wv & 1;     // 2M x 2N wave grid, wave tile 32x32

  const int gx = gridDim.x, gy = gridDim.y;
  const int id = blockIdx.x + gx * (blockIdx.y + gy * blockIdx.z);
  const int xcd = id & 7, q = id >> 3;     // q in [0,256)

  int bm0, bn0, bz, kbeg;
  if (MODE == 0) {
    const int mx = (xcd & 1) * 16 + (q & 15);        // 0..31
    const int nx = (xcd >> 1) * 16 + (q >> 4);       // 0..63
    bm0 = mx * 64; bn0 = nx * 64; bz = 0; kbeg = 0;
  } else {
    bz = xcd >> 1;                                   // 0..3
    const int by = (xcd & 1) * 16 + (q & 15);        // 0..31
    const int bx = q >> 4;                           // 0..15
    bm0 = by * 64; bn0 = bx * 64; kbeg = bz * (Kstride >> 2);
  }
  const int kchunk = (MODE == 0) ? Kstride : (Kstride >> 2);
  const int nkt = kchunk / 128;            // 8 big-steps for both GEMMs

  const int srow = lane >> 3;              // 0..7
  const int gslot = (lane & 7) ^ srow;     // inverse-swizzled global 16B slot

  float4v acc[2][2];
#pragma unroll
  for (int i = 0; i < 2; i++)
#pragma unroll
    for (int j = 0; j < 2; j++) acc[i][j] = (float4v){0.f, 0.f, 0.f, 0.f};

  for (int t = 0; t < nkt; ++t) {
    const int k0 = kbeg + t * 128;
    __syncthreads();   // all waves done reading previous big-step
#pragma unroll
    for (int p = 0; p < 2; p++) {          // two 64-wide K-planes
#pragma unroll
      for (int i = 0; i < 2; i++) {        // 2 row-groups of 32
        const int row = i * 32 + wv * 8 + srow;
        const int chunkbase = i * 256 + wv * 64;
        GLD16(Ag + (size_t)(bm0 + row) * Kstride + k0 + p * 64 + gslot * 8, &lA[p][chunkbase * 8]);
        GLD16(Bg + (size_t)(bn0 + row) * Kstride + k0 + p * 64 + gslot * 8, &lB[p][chunkbase * 8]);
      }
    }
    __syncthreads();   // one drain+barrier per 128 K
#pragma unroll
    for (int kk = 0; kk < 4; kk++) {
      const int pl = kk >> 1;
      const int s = (lane >> 4) + (kk & 1) * 4;   // 16B k-slot 0..7 within plane
      short8v af[2], bfr[2];
#pragma unroll
      for (int mi = 0; mi < 2; mi++) {
        const int rr = wr * 32 + mi * 16 + (lane & 15);
        af[mi] = *(const short8v*)&lA[pl][rr * 64 + (s ^ (rr & 7)) * 8];
      }
#pragma unroll
      for (int nj = 0; nj < 2; nj++) {
        const int rr = wc * 32 + nj * 16 + (lane & 15);
        bfr[nj] = *(const short8v*)&lB[pl][rr * 64 + (s ^ (rr & 7)) * 8];
      }
#pragma unroll
      for (int mi = 0; mi < 2; mi++)
#pragma unroll
        for (int nj = 0; nj < 2; nj++)
          acc[mi][nj] = __builtin_amdgcn_mfma_f32_16x16x32_bf16(af[mi], bfr[nj], acc[mi][nj], 0, 0, 0);
    }
  }

  if (MODE == 0) {
#pragma unroll
    for (int mi = 0; mi < 2; mi++) {
      int r0 = bm0 + wr * 32 + mi * 16 + ((lane >> 4) << 2);
#pragma unroll
      for (int nj = 0; nj < 2; nj++) {
        int cc = bn0 + wc * 32 + nj * 16 + (lane & 15);
#pragma unroll
        for (int r = 0; r < 4; r++) {
          float xv = acc[mi][nj][r];
          // gelu(x) = 0.5x(1+tanh(u)) == x * sigmoid(2u); u = 0.79788456(x+0.044715x^3)
          float u = 0.7978845608028654f * (xv + 0.044715f * xv * xv * xv);
          float g = xv / (1.f + __expf(-2.f * u));
          Hout[(size_t)(r0 + r) * FF + cc] = f2bf(g);
        }
      }
    }
  } else {
    ushort_t* Op = Oacc + (size_t)bz * MTOT * DD;   // disjoint bf16 partial per K-split
#pragma unroll
    for (int mi = 0; mi < 2; mi++) {
      int tr0 = bm0 + wr * 32 + mi * 16 + ((lane >> 4) << 2);
#pragma unroll
      for (int r = 0; r < 4; r++) {
        ushort_t* orow = Op + (size_t)(tr0 + r) * DD + bn0 + wc * 32 + (lane & 15);
#pragma unroll
        for (int nj = 0; nj < 2; nj++) orow[nj * 16] = f2bf(acc[mi][nj][r]);
      }
    }
  }
}

extern "C" void kernel_launch(void* const* d_in, const int* in_sizes, int n_in,
                              void* d_out, int out_size, void* d_ws, size_t ws_size,
                              hipStream_t stream) {
  (void)in_sizes; (void)n_in; (void)out_size; (void)ws_size;
  const float* x  = (const float*)d_in[0];
  const float* wrt = (const float*)d_in[1];
  const float* W1 = (const float*)d_in[2];
  const float* W2 = (const float*)d_in[3];
  float* out = (float*)d_out;
  char* ws = (char*)d_ws;
  float*    rw   = (float*)(ws + OFF_RW);
  int*      idxs = (int*)(ws + OFF_IDX);
  float*    wtop = (float*)(ws + OFF_WTOP);
  float*    lossP= (float*)(ws + OFF_LOSS);
  int*      posm = (int*)(ws + OFF_POS);
  int*      rnk  = (int*)(ws + OFF_RANK);
  ushort_t* A    = (ushort_t*)(ws + OFF_A);
  ushort_t* W1T  = (ushort_t*)(ws + OFF_W1T);
  ushort_t* W2T  = (ushort_t*)(ws + OFF_W2T);
  ushort_t* H    = (ushort_t*)(ws + OFF_H);
  ushort_t* O    = (ushort_t*)(ws + OFF_O);

  // no memsets: every scratch value consumed is written each call
  router_kernel<<<dim3(BB * SS / 4), dim3(256), 0, stream>>>(x, wrt, rw);
  rank_kernel<<<dim3(SS / 64, BB), dim3(256), 0, stream>>>(rw, rnk);
  finalize_kernel<<<dim3(BB), dim3(1024), 0, stream>>>(rw, rnk, idxs, wtop, posm, lossP);
  // prep: W1/W2 transposes (8192 blocks) + A gather (2048 blocks), one launch
  prep_kernel<<<dim3(8192 + MTOT), dim3(256), 0, stream>>>(W1, W1T, W2, W2T, x, idxs, A);
  // GEMM1: [2048x1024]*[4096x1024]^T -> gelu -> H    grid (64,32)=2048 blocks
  gemm_oc<0><<<dim3(FF / 64, MTOT / 64, 1), dim3(256), 0, stream>>>(A, W1T, DD, H, nullptr);
  // GEMM2: [2048x4096]*[1024x4096]^T -> 4 bf16 direct-store partials, grid (16,32,4)
  gemm_oc<1><<<dim3(DD / 64, MTOT / 64, 4), dim3(256), 0, stream>>>(H, W2T, FF, nullptr, O);
  // final: every d_out row written exactly once; loss element in block 0
  scatter_kernel<<<dim3(BB * SS), dim3(256), 0, stream>>>(O, posm, wtop, lossP, out);
}